// Round 7
// baseline (1715.923 us; speedup 1.0000x reference)
//
#include <hip/hip_runtime.h>
#include <hip/hip_bf16.h>

#define BB   128
#define SS   256
#define DD   512
#define HH   1024
#define NCC  128
#define NCLS 129
#define G4   4096   // 4*HH, gate-interleaved: j = hcol*4 + gate (f,i,g,o)
#define NWG  256    // persistent grid size

typedef __attribute__((ext_vector_type(8)))  short  short8;
typedef __attribute__((ext_vector_type(16))) float  f32x16;

static __device__ __forceinline__ float sigm(float x)  { return 1.0f / (1.0f + __expf(-x)); }
static __device__ __forceinline__ float tanh_(float x) { return 1.0f - 2.0f / (__expf(2.0f * x) + 1.0f); }
static __device__ __forceinline__ unsigned short f2b(float v) {
    __hip_bfloat16 h = __float2bfloat16(v);
    return *reinterpret_cast<unsigned short*>(&h);
}
static __device__ __forceinline__ short8 ld16(const unsigned short* p) {
    return *reinterpret_cast<const short8*>(p);
}

// ---------------- fused preamble: init + Wh-conv + proj (independent jobs) ----
// blocks [0,512)      : zero-init h buffer 0 and flag/counter block
// blocks [512,4608)   : Wh -> bf16, transposed, gate-interleaved
// blocks [4608,6672)  : proj[c][j] = emb[c,:] @ Wx[:,hcol] + b
__global__ void k_pre(unsigned short* __restrict__ hb0, int* __restrict__ flags,
                      const float* __restrict__ Wfh, const float* __restrict__ Wih,
                      const float* __restrict__ Wgh, const float* __restrict__ Woh,
                      unsigned short* __restrict__ WhT,
                      const float* __restrict__ emb,
                      const float* __restrict__ Wfx, const float* __restrict__ Wix,
                      const float* __restrict__ Wgx, const float* __restrict__ Wox,
                      const float* __restrict__ bf_, const float* __restrict__ bi_,
                      const float* __restrict__ bg_, const float* __restrict__ bo_,
                      float* __restrict__ proj) {
    __shared__ float t[32][33];
    const int bid = blockIdx.x;
    if (bid < 512) {
        int i = bid * 256 + threadIdx.x;
        if (i < BB * HH) hb0[i] = 0;
        if (i < 16384) flags[i] = 0;
        return;
    }
    if (bid < 4608) {
        int b = bid - 512;
        int bx = b & 31, by = (b >> 5) & 31, g = b >> 10;
        const float* W = (g == 0) ? Wfh : (g == 1) ? Wih : (g == 2) ? Wgh : Woh;
        int h0 = bx * 32, k0 = by * 32;
        int tx = threadIdx.x & 31, ty = threadIdx.x >> 5;
        for (int r = 0; r < 4; r++) {
            int k = ty + r * 8;
            t[k][tx] = W[(size_t)(k0 + k) * HH + h0 + tx];
        }
        __syncthreads();
        for (int r = 0; r < 4; r++) {
            int hl = ty + r * 8;
            int j  = (h0 + hl) * 4 + g;
            WhT[(size_t)j * HH + k0 + tx] = f2b(t[tx][hl]);
        }
        return;
    }
    {
        int b = bid - 4608;
        int c = b >> 4;
        int j = (b & 15) * 256 + threadIdx.x;
        int hcol = j >> 2, g = j & 3;
        const float* Wx = (g == 0) ? Wfx : (g == 1) ? Wix : (g == 2) ? Wgx : Wox;
        const float* bb = (g == 0) ? bf_ : (g == 1) ? bi_ : (g == 2) ? bg_ : bo_;
        float acc = bb[hcol];
        const float* er = emb + (size_t)c * DD;
        for (int d = 0; d < DD; d++) acc += er[d] * Wx[(size_t)d * HH + hcol];
        proj[(size_t)c * G4 + j] = acc;
    }
}

// ---- L2-bypassing 16B load from rolling base (h is cross-XCD dynamic data)
#define LDAB(d, B, L) asm volatile("global_load_dwordx4 %0, %1, off offset:" L " sc0 sc1" \
                                   : "=v"(d) : "v"(B))
// 4 contiguous 1KB loads then advance base 4KB (13-bit offset limit)
#define LD4(A, I) do { \
    LDAB(A[(I)+0], p, "0"); LDAB(A[(I)+1], p, "1024"); \
    LDAB(A[(I)+2], p, "2048"); LDAB(A[(I)+3], p, "3072"); p += 4096; } while (0)
#define LD16(A) do { LD4(A,0); LD4(A,4); LD4(A,8); LD4(A,12); } while (0)

// ---- waitcnt with data-tie so MFMAs can't be scheduled before the wait
#define WAITA(N, A) asm volatile("s_waitcnt vmcnt(" N ")" : \
    "+v"(A[0]),"+v"(A[1]),"+v"(A[2]),"+v"(A[3]),"+v"(A[4]),"+v"(A[5]),"+v"(A[6]),"+v"(A[7]), \
    "+v"(A[8]),"+v"(A[9]),"+v"(A[10]),"+v"(A[11]),"+v"(A[12]),"+v"(A[13]),"+v"(A[14]),"+v"(A[15]))

// 4 accumulator chains: same-acc reuse gap = 4 MFMAs (~32 cy) >= MFMA latency,
// so the chain never stalls on the accumulator dependency (2-chain gap ~16cy did).
#define MM(a, b, c) __builtin_amdgcn_mfma_f32_32x32x16_bf16(a, b, c, 0, 0, 0)
#define MF16(A, KB) do { \
    acc0 = MM(A[0],  breg[(KB)+0],  acc0); \
    acc1 = MM(A[1],  breg[(KB)+1],  acc1); \
    acc2 = MM(A[2],  breg[(KB)+2],  acc2); \
    acc3 = MM(A[3],  breg[(KB)+3],  acc3); \
    acc0 = MM(A[4],  breg[(KB)+4],  acc0); \
    acc1 = MM(A[5],  breg[(KB)+5],  acc1); \
    acc2 = MM(A[6],  breg[(KB)+6],  acc2); \
    acc3 = MM(A[7],  breg[(KB)+7],  acc3); \
    acc0 = MM(A[8],  breg[(KB)+8],  acc0); \
    acc1 = MM(A[9],  breg[(KB)+9],  acc1); \
    acc2 = MM(A[10], breg[(KB)+10], acc2); \
    acc3 = MM(A[11], breg[(KB)+11], acc3); \
    acc0 = MM(A[12], breg[(KB)+12], acc0); \
    acc1 = MM(A[13], breg[(KB)+13], acc1); \
    acc2 = MM(A[14], breg[(KB)+14], acc2); \
    acc3 = MM(A[15], breg[(KB)+15], acc3); \
} while (0)

// 16 gathered proj loads (normal caching) for step ST, classes from the
// LDS-resident x table. Issued right AFTER barrier detect -> RT hides under
// the next step's A-load + MFMA phase; drained by that phase's first WAITA.
#define PRLOAD(DSTA, ST) do { \
    _Pragma("unroll") \
    for (int r = 0; r < 16; r++) { \
        int row = (r & 3) + 8 * (r >> 2) + 4 * half; \
        const float* pa = proj + (size_t)xtab[row][ST] * G4 + jg; \
        asm volatile("global_load_dword %0, %1, off" : "=v"(DSTA[r]) \
                     : "v"((unsigned long long)pa)); \
    } \
} while (0)

// ---------------- persistent LSTM scan ----------------
// 256 WGs x 128 thr (2 waves). WG(mg = wg&3, ng = wg>>2): rows mg*32..+32,
// gate-cols ng*64..+64. WhT slice in registers (full K).
// h stored FRAGMENT-MAJOR: hF[mg][kk][lane][8bf16] so A-loads are 64 x 1KB
// fully-contiguous sector-perfect streams (lane l: m = l&31, k = kk*16+(l>>5)*8+j).
// ONE-HOP barrier per mg-group, arrivals spread over 8 lines (r6-proven):
// atomic_add(+1) on line (ng&7) after the h-store drain; ONE wide poll (lane l
// watches line l&7, ballot-exit). x class ids preloaded to LDS once (stride-257
// padding -> conflict-free), so the per-step drain covers ONLY the h-stores.
__global__ __launch_bounds__(128, 1)
void k_scan(const int* __restrict__ x, const float* __restrict__ proj,
            const unsigned short* __restrict__ WhT,
            unsigned short* __restrict__ hb0, unsigned short* __restrict__ hb1,
            float* __restrict__ hf32, int* __restrict__ flags) {
    const int wg = blockIdx.x, tid = threadIdx.x;
    const int lane = tid & 63, wv = tid >> 6;
    const int l31 = lane & 31, half = lane >> 5;
    const int mg = wg & 3, ng = wg >> 2;
    const int m0 = mg * 32, n0 = ng * 64;
    const int jg = n0 + wv * 32 + l31;       // this lane's gate-col

    // B fragments: WhT[jg][k], k = kk*16 + half*8 + j  (256 regs)
    short8 breg[64];
    {
        const unsigned short* Bp = WhT + (size_t)jg * HH + half * 8;
        #pragma unroll
        for (int kk = 0; kk < 64; kk++) breg[kk] = ld16(Bp + kk * 16);
    }

    __shared__ float sg[32][68];     // sigmoided gates [row][gate-col]
    __shared__ int   xtab[32][257];  // class ids [row][step], padded stride

    // preload the full class table once (coalesced reads, conflict-free writes)
    for (int i = tid; i < 32 * SS; i += 128) {
        int row = i >> 8, st = i & 255;
        xtab[row][st] = x[(size_t)(m0 + row) * SS + st];
    }
    __syncthreads();

    float Cst[4] = {0.0f, 0.0f, 0.0f, 0.0f};
    const int urow = tid & 31, uq = tid >> 5;

    // fragment-major bases: hF byte offset = mg*65536 + kk*1024 + lane*16
    const unsigned long long ab0 =
        (unsigned long long)((char*)hb0 + mg * 65536 + lane * 16);
    const unsigned long long ab1 =
        (unsigned long long)((char*)hb1 + mg * 65536 + lane * 16);
    // producer store base: cell = urow + 32*(uq>>1), sub = (uq&1)*8 bytes
    const unsigned long long sb0 = (unsigned long long)((char*)hb0 + mg * 65536
        + ng * 1024 + (urow + ((uq >> 1) << 5)) * 16 + (uq & 1) * 8);
    const unsigned long long sb1 = (unsigned long long)((char*)hb1 + mg * 65536
        + ng * 1024 + (urow + ((uq >> 1) << 5)) * 16 + (uq & 1) * 8);

    // 8 arrival lines per mg-group, 128B-strided (zeroed by k_pre):
    // this WG adds to line (ng&7); poll reads line (lane&7).
    const unsigned long long ctrAddr =
        (unsigned long long)(flags + (size_t)(8192 + mg * 256 + (ng & 7) * 32));
    const unsigned long long pollAddr =
        (unsigned long long)(flags + (size_t)(8192 + mg * 256 + (lane & 7) * 32));

    float pr[16];
    PRLOAD(pr, 0);                  // step-0 proj gather (drained by first WAITA)

    for (int s = 0; s < SS; s++) {
        const int cur = s & 1;
        unsigned long long p = cur ? ab1 : ab0;
        const unsigned long long sb = cur ? sb0 : sb1;   // store to the OTHER buffer

        // ---- pipelined A loads: 4 groups x 16 x 1KB contiguous ----
        // vmcnt ledger at loop top: 16 proj loads outstanding (oldest).
        short8 a0[16], a1[16], a2[16], a3[16];
        LD16(a0);
        LD16(a1);

        f32x16 acc0, acc1, acc2, acc3;
        #pragma unroll
        for (int r = 0; r < 16; r++) { acc0[r] = 0.0f; acc1[r] = 0.0f;
                                       acc2[r] = 0.0f; acc3[r] = 0.0f; }

        WAITA("16", a0);    // drains proj(16)+a0(16), leaves a1 in flight
        LD16(a2);
        MF16(a0, 0);
        WAITA("16", a1);    // drains a1, leaves a2
        LD16(a3);
        MF16(a1, 16);
        WAITA("16", a2);    // drains a2, leaves a3
        MF16(a2, 32);
        WAITA("0", a3);
        MF16(a3, 48);

        // ---- epilogue: sum 4 chains + preloaded proj, sigmoid, stash in LDS ----
        // C/D layout (m74/m101): col = lane&31, row = (r&3) + 8*(r>>2) + 4*(lane>>5)
        #pragma unroll
        for (int r = 0; r < 16; r++) {
            int row = (r & 3) + 8 * (r >> 2) + 4 * half;
            sg[row][wv * 32 + l31] =
                sigm(((acc0[r] + acc1[r]) + (acc2[r] + acc3[r])) + pr[r]);
        }
        __syncthreads();

        // ---- pointwise: thread owns (row = tid&31, hcols uq*4..+4) ----
        {
            const float rr = (xtab[urow][s] > 0) ? 1.0f : 0.0f;
            unsigned short hv[4];
            #pragma unroll
            for (int q = 0; q < 4; q++) {
                float4 gq = *reinterpret_cast<const float4*>(&sg[urow][uq * 16 + q * 4]);
                float cn = (gq.z * gq.y + Cst[q] * gq.x) * rr;   // (g*i + C*f)*r
                Cst[q] = cn;
                float hvv = gq.w * tanh_(cn);
                hv[q] = f2b(hvv);
                if (s == SS - 1)
                    hf32[(size_t)(m0 + urow) * HH + ng * 16 + uq * 4 + q] = hvv;
            }
            unsigned long long pk = (unsigned long long)hv[0]
                                  | ((unsigned long long)hv[1] << 16)
                                  | ((unsigned long long)hv[2] << 32)
                                  | ((unsigned long long)hv[3] << 48);
            asm volatile("global_store_dwordx2 %0, %1, off sc0 sc1" :: "v"(sb), "v"(pk) : "memory");
        }

        // ---- one-hop barrier: drain h-stores, spread atomic arrival, wide poll ----
        if (s < SS - 1) {
            asm volatile("s_waitcnt vmcnt(0)" ::: "memory");   // pure h-store drain
            __syncthreads();
            if (tid == 0) {
                int one = 1;
                asm volatile("global_atomic_add %0, %1, off"
                             :: "v"(ctrAddr), "v"(one) : "memory");
            }
            const int tv = (s + 1) << 3;   // 8 WGs per arrival line
            int got;
            do {   // one wide poll: lane l watches line l&7 (single RT/iter)
                asm volatile("global_load_dword %0, %1, off sc0 sc1\n\t"
                             "s_waitcnt vmcnt(0)"
                             : "=v"(got) : "v"(pollAddr) : "memory");
            } while (__ballot(got >= tv) != ~0ull);
            PRLOAD(pr, s + 1);   // issued at detect; RT hides under next A/MFMA phase
        }
    }
}

// ---------------- final projection + log_softmax ----------------
__global__ void k_final(const float* __restrict__ hf32, const float* __restrict__ Wph,
                        const float* __restrict__ bp, float* __restrict__ out) {
    __shared__ float red[128];
    int b = blockIdx.x, c = threadIdx.x;
    const float* hr = hf32 + (size_t)b * HH;
    float acc = bp[c];
    for (int k = 0; k < HH; k++) acc += hr[k] * Wph[(size_t)k * NCC + c];
    red[c] = acc;
    __syncthreads();
    for (int st = 64; st > 0; st >>= 1) {
        if (c < st) red[c] = fmaxf(red[c], red[c + st]);
        __syncthreads();
    }
    float m = red[0];
    __syncthreads();
    red[c] = __expf(acc - m);
    __syncthreads();
    for (int st = 64; st > 0; st >>= 1) {
        if (c < st) red[c] += red[c + st];
        __syncthreads();
    }
    out[(size_t)b * NCC + c] = acc - m - __logf(red[0]);
}

extern "C" void kernel_launch(void* const* d_in, const int* in_sizes, int n_in,
                              void* d_out, int out_size, void* d_ws, size_t ws_size,
                              hipStream_t stream) {
    const int*   x   = (const int*)  d_in[0];
    const float* emb = (const float*)d_in[1];
    const float* Wfx = (const float*)d_in[2];
    const float* Wfh = (const float*)d_in[3];
    const float* bf_ = (const float*)d_in[4];
    const float* Wix = (const float*)d_in[5];
    const float* Wih = (const float*)d_in[6];
    const float* bi_ = (const float*)d_in[7];
    const float* Wgx = (const float*)d_in[8];
    const float* Wgh = (const float*)d_in[9];
    const float* bg_ = (const float*)d_in[10];
    const float* Wox = (const float*)d_in[11];
    const float* Woh = (const float*)d_in[12];
    const float* bo_ = (const float*)d_in[13];
    const float* Wph = (const float*)d_in[14];
    const float* bp_ = (const float*)d_in[15];
    float* out = (float*)d_out;

    char* ws = (char*)d_ws;
    unsigned short* WhT   = (unsigned short*)(ws);              // 8 MB
    float*          proj  = (float*)(ws + 8388608);             // 2.02 MB -> ends 10502144
    int*            flags = (int*)(ws + 10502656);              // 64 KB (16384 ints)
    unsigned short* hb0   = (unsigned short*)(ws + 10568192);   // 256 KB
    unsigned short* hb1   = (unsigned short*)(ws + 10830336);   // 256 KB
    float*          hf32  = (float*)(ws + 11092480);            // 512 KB -> ends ~11.6 MB

    k_pre<<<dim3(6672), dim3(256), 0, stream>>>(hb0, flags, Wfh, Wih, Wgh, Woh, WhT,
                                                emb, Wfx, Wix, Wgx, Wox,
                                                bf_, bi_, bg_, bo_, proj);
    k_scan<<<dim3(NWG), dim3(128), 0, stream>>>(x, proj, WhT, hb0, hb1, hf32, flags);
    k_final<<<dim3(128), dim3(128), 0, stream>>>(hf32, Wph, bp_, out);
}

// Round 8
// 1368.775 us; speedup vs baseline: 1.2536x; 1.2536x over previous
//
#include <hip/hip_runtime.h>
#include <hip/hip_bf16.h>

#define BB   128
#define SS   256
#define DD   512
#define HH   1024
#define NCC  128
#define NCLS 129
#define G4   4096   // 4*HH, gate-interleaved: j = hcol*4 + gate (f,i,g,o)
#define NWG  256    // persistent grid size

typedef __attribute__((ext_vector_type(8)))  short  short8;
typedef __attribute__((ext_vector_type(16))) float  f32x16;

static __device__ __forceinline__ float sigm(float x)  { return 1.0f / (1.0f + __expf(-x)); }
static __device__ __forceinline__ float tanh_(float x) { return 1.0f - 2.0f / (__expf(2.0f * x) + 1.0f); }
static __device__ __forceinline__ unsigned short f2b(float v) {
    __hip_bfloat16 h = __float2bfloat16(v);
    return *reinterpret_cast<unsigned short*>(&h);
}
static __device__ __forceinline__ short8 ld16(const unsigned short* p) {
    return *reinterpret_cast<const short8*>(p);
}

// ---------------- fused preamble: init + Wh-conv + proj (independent jobs) ----
// blocks [0,512)      : zero-init h buffer 0 and flag/counter block
// blocks [512,4608)   : Wh -> bf16, transposed, gate-interleaved
// blocks [4608,6672)  : proj[c][j] = emb[c,:] @ Wx[:,hcol] + b
__global__ void k_pre(unsigned short* __restrict__ hb0, int* __restrict__ flags,
                      const float* __restrict__ Wfh, const float* __restrict__ Wih,
                      const float* __restrict__ Wgh, const float* __restrict__ Woh,
                      unsigned short* __restrict__ WhT,
                      const float* __restrict__ emb,
                      const float* __restrict__ Wfx, const float* __restrict__ Wix,
                      const float* __restrict__ Wgx, const float* __restrict__ Wox,
                      const float* __restrict__ bf_, const float* __restrict__ bi_,
                      const float* __restrict__ bg_, const float* __restrict__ bo_,
                      float* __restrict__ proj) {
    __shared__ float t[32][33];
    const int bid = blockIdx.x;
    if (bid < 512) {
        int i = bid * 256 + threadIdx.x;
        if (i < BB * HH) hb0[i] = 0;
        if (i < 16384) flags[i] = 0;
        return;
    }
    if (bid < 4608) {
        int b = bid - 512;
        int bx = b & 31, by = (b >> 5) & 31, g = b >> 10;
        const float* W = (g == 0) ? Wfh : (g == 1) ? Wih : (g == 2) ? Wgh : Woh;
        int h0 = bx * 32, k0 = by * 32;
        int tx = threadIdx.x & 31, ty = threadIdx.x >> 5;
        for (int r = 0; r < 4; r++) {
            int k = ty + r * 8;
            t[k][tx] = W[(size_t)(k0 + k) * HH + h0 + tx];
        }
        __syncthreads();
        for (int r = 0; r < 4; r++) {
            int hl = ty + r * 8;
            int j  = (h0 + hl) * 4 + g;
            WhT[(size_t)j * HH + k0 + tx] = f2b(t[tx][hl]);
        }
        return;
    }
    {
        int b = bid - 4608;
        int c = b >> 4;
        int j = (b & 15) * 256 + threadIdx.x;
        int hcol = j >> 2, g = j & 3;
        const float* Wx = (g == 0) ? Wfx : (g == 1) ? Wix : (g == 2) ? Wgx : Wox;
        const float* bb = (g == 0) ? bf_ : (g == 1) ? bi_ : (g == 2) ? bg_ : bo_;
        float acc = bb[hcol];
        const float* er = emb + (size_t)c * DD;
        for (int d = 0; d < DD; d++) acc += er[d] * Wx[(size_t)d * HH + hcol];
        proj[(size_t)c * G4 + j] = acc;
    }
}

// ---- L2-bypassing 16B load from rolling base (h is cross-XCD dynamic data)
#define LDAB(d, B, L) asm volatile("global_load_dwordx4 %0, %1, off offset:" L " sc0 sc1" \
                                   : "=v"(d) : "v"(B))
// 4 contiguous 1KB loads then advance base 4KB (13-bit offset limit)
#define LD4(A, I) do { \
    LDAB(A[(I)+0], p, "0"); LDAB(A[(I)+1], p, "1024"); \
    LDAB(A[(I)+2], p, "2048"); LDAB(A[(I)+3], p, "3072"); p += 4096; } while (0)
#define LD16(A) do { LD4(A,0); LD4(A,4); LD4(A,8); LD4(A,12); } while (0)

// ---- waitcnt with data-tie so MFMAs can't be scheduled before the wait
#define WAITA(N, A) asm volatile("s_waitcnt vmcnt(" N ")" : \
    "+v"(A[0]),"+v"(A[1]),"+v"(A[2]),"+v"(A[3]),"+v"(A[4]),"+v"(A[5]),"+v"(A[6]),"+v"(A[7]), \
    "+v"(A[8]),"+v"(A[9]),"+v"(A[10]),"+v"(A[11]),"+v"(A[12]),"+v"(A[13]),"+v"(A[14]),"+v"(A[15]))

// 4 accumulator chains: same-acc reuse gap = 4 MFMAs (~32 cy) >= MFMA result
// latency, so the 64-MFMA phase issues stall-free (2-chain gap ~16 cy stalled).
#define MM(a, b, c) __builtin_amdgcn_mfma_f32_32x32x16_bf16(a, b, c, 0, 0, 0)
#define MF16(A, KB) do { \
    acc0 = MM(A[0],  breg[(KB)+0],  acc0); \
    acc1 = MM(A[1],  breg[(KB)+1],  acc1); \
    acc2 = MM(A[2],  breg[(KB)+2],  acc2); \
    acc3 = MM(A[3],  breg[(KB)+3],  acc3); \
    acc0 = MM(A[4],  breg[(KB)+4],  acc0); \
    acc1 = MM(A[5],  breg[(KB)+5],  acc1); \
    acc2 = MM(A[6],  breg[(KB)+6],  acc2); \
    acc3 = MM(A[7],  breg[(KB)+7],  acc3); \
    acc0 = MM(A[8],  breg[(KB)+8],  acc0); \
    acc1 = MM(A[9],  breg[(KB)+9],  acc1); \
    acc2 = MM(A[10], breg[(KB)+10], acc2); \
    acc3 = MM(A[11], breg[(KB)+11], acc3); \
    acc0 = MM(A[12], breg[(KB)+12], acc0); \
    acc1 = MM(A[13], breg[(KB)+13], acc1); \
    acc2 = MM(A[14], breg[(KB)+14], acc2); \
    acc3 = MM(A[15], breg[(KB)+15], acc3); \
} while (0)

// 16 gathered proj loads (normal caching), completed by the poll's vmcnt(0)
#define PRLOAD(DSTA, CLSBUF) do { \
    _Pragma("unroll") \
    for (int r = 0; r < 16; r++) { \
        int row = (r & 3) + 8 * (r >> 2) + 4 * half; \
        const float* pa = proj + (size_t)CLSBUF[row] * G4 + jg; \
        asm volatile("global_load_dword %0, %1, off" : "=v"(DSTA[r]) \
                     : "v"((unsigned long long)pa)); \
    } \
} while (0)

// ---------------- persistent LSTM scan ----------------
// 256 WGs x 128 thr (2 waves). WG(mg = wg&3, ng = wg>>2): rows mg*32..+32,
// gate-cols ng*64..+64. WhT slice in registers (full K).
// h stored FRAGMENT-MAJOR: hF[mg][kk][lane][8bf16] so A-loads are 64 x 1KB
// fully-contiguous sector-perfect streams (lane l: m = l&31, k = kk*16+(l>>5)*8+j).
// ONE-HOP barrier per mg-group, arrivals SPREAD OVER 8 LINES (8 WGs each,
// line = ng&7): fire-and-forget atomic_add(+1) after h-stores drain ->
// serialization depth 8 (parallel L3 slices) instead of 64. Detection is ONE
// wide poll: lane l reads line l&7, exit when ballot(got >= 8*(s+1)) all-set.
// PRLOAD stays BEFORE the poll (r7 lesson: moving it after detect puts the
// scattered gather RT serially at the step head, -35%).
__global__ __launch_bounds__(128, 1)
void k_scan(const int* __restrict__ x, const float* __restrict__ proj,
            const unsigned short* __restrict__ WhT,
            unsigned short* __restrict__ hb0, unsigned short* __restrict__ hb1,
            float* __restrict__ hf32, int* __restrict__ flags) {
    const int wg = blockIdx.x, tid = threadIdx.x;
    const int lane = tid & 63, wv = tid >> 6;
    const int l31 = lane & 31, half = lane >> 5;
    const int mg = wg & 3, ng = wg >> 2;
    const int m0 = mg * 32, n0 = ng * 64;
    const int jg = n0 + wv * 32 + l31;       // this lane's gate-col

    // B fragments: WhT[jg][k], k = kk*16 + half*8 + j  (256 regs)
    short8 breg[64];
    {
        const unsigned short* Bp = WhT + (size_t)jg * HH + half * 8;
        #pragma unroll
        for (int kk = 0; kk < 64; kk++) breg[kk] = ld16(Bp + kk * 16);
    }

    __shared__ float sg[32][68];    // sigmoided gates [row][gate-col]
    __shared__ int   clsS[2][32];   // double-buffered class ids

    float Cst[4] = {0.0f, 0.0f, 0.0f, 0.0f};
    const int urow = tid & 31, uq = tid >> 5;

    if (tid < 32) clsS[0][tid] = x[(size_t)(m0 + tid) * SS];
    __syncthreads();

    // fragment-major bases: hF byte offset = mg*65536 + kk*1024 + lane*16
    const unsigned long long ab0 =
        (unsigned long long)((char*)hb0 + mg * 65536 + lane * 16);
    const unsigned long long ab1 =
        (unsigned long long)((char*)hb1 + mg * 65536 + lane * 16);
    // producer store base: cell = urow + 32*(uq>>1), sub = (uq&1)*8 bytes
    const unsigned long long sb0 = (unsigned long long)((char*)hb0 + mg * 65536
        + ng * 1024 + (urow + ((uq >> 1) << 5)) * 16 + (uq & 1) * 8);
    const unsigned long long sb1 = (unsigned long long)((char*)hb1 + mg * 65536
        + ng * 1024 + (urow + ((uq >> 1) << 5)) * 16 + (uq & 1) * 8);

    // 8 arrival lines per mg-group, 128B-strided (zeroed by k_pre):
    // this WG adds to line (ng&7); poll reads line (lane&7).
    const unsigned long long ctrAddr =
        (unsigned long long)(flags + (size_t)(8192 + mg * 256 + (ng & 7) * 32));
    const unsigned long long pollAddr =
        (unsigned long long)(flags + (size_t)(8192 + mg * 256 + (lane & 7) * 32));

    float pr[16];
    PRLOAD(pr, clsS[0]);            // step-0 proj gather (drained by first WAITA)

    for (int s = 0; s < SS; s++) {
        const int cur = s & 1;
        unsigned long long p = cur ? ab1 : ab0;
        const unsigned long long sb = cur ? sb0 : sb1;   // store to the OTHER buffer

        // ---- pipelined A loads: 4 groups x 16 x 1KB contiguous ----
        short8 a0[16], a1[16], a2[16], a3[16];
        LD16(a0);
        LD16(a1);

        f32x16 acc0, acc1, acc2, acc3;
        #pragma unroll
        for (int r = 0; r < 16; r++) { acc0[r] = 0.0f; acc1[r] = 0.0f;
                                       acc2[r] = 0.0f; acc3[r] = 0.0f; }

        WAITA("16", a0);
        LD16(a2);
        MF16(a0, 0);
        WAITA("16", a1);
        LD16(a3);
        MF16(a1, 16);
        WAITA("16", a2);
        MF16(a2, 32);
        WAITA("0", a3);
        MF16(a3, 48);

        // ---- epilogue: sum 4 chains + preloaded proj, sigmoid, stash in LDS ----
        // C/D layout (m74/m101): col = lane&31, row = (r&3) + 8*(r>>2) + 4*(lane>>5)
        #pragma unroll
        for (int r = 0; r < 16; r++) {
            int row = (r & 3) + 8 * (r >> 2) + 4 * half;
            sg[row][wv * 32 + l31] =
                sigm(((acc0[r] + acc1[r]) + (acc2[r] + acc3[r])) + pr[r]);
        }
        __syncthreads();

        // ---- pointwise: thread owns (row = tid&31, hcols uq*4..+4) ----
        {
            const float rr = (clsS[cur][urow] > 0) ? 1.0f : 0.0f;
            unsigned short hv[4];
            #pragma unroll
            for (int q = 0; q < 4; q++) {
                float4 gq = *reinterpret_cast<const float4*>(&sg[urow][uq * 16 + q * 4]);
                float cn = (gq.z * gq.y + Cst[q] * gq.x) * rr;   // (g*i + C*f)*r
                Cst[q] = cn;
                float hvv = gq.w * tanh_(cn);
                hv[q] = f2b(hvv);
                if (s == SS - 1)
                    hf32[(size_t)(m0 + urow) * HH + ng * 16 + uq * 4 + q] = hvv;
            }
            unsigned long long pk = (unsigned long long)hv[0]
                                  | ((unsigned long long)hv[1] << 16)
                                  | ((unsigned long long)hv[2] << 32)
                                  | ((unsigned long long)hv[3] << 48);
            asm volatile("global_store_dwordx2 %0, %1, off sc0 sc1" :: "v"(sb), "v"(pk) : "memory");
            if (s + 1 < SS && tid < 32)
                clsS[cur ^ 1][tid] = x[(size_t)(m0 + tid) * SS + s + 1];
        }

        // ---- one-hop barrier: drain h-stores, spread atomic arrival, wide poll ----
        if (s < SS - 1) {
            asm volatile("s_waitcnt vmcnt(0)" ::: "memory");   // h-store drained at L3
            __syncthreads();
            if (tid == 0) {
                int one = 1;
                asm volatile("global_atomic_add %0, %1, off"
                             :: "v"(ctrAddr), "v"(one) : "memory");
            }
            PRLOAD(pr, clsS[cur ^ 1]);     // next step's proj gather, rides the poll
            const int tv = (s + 1) << 3;   // 8 WGs per arrival line
            int got;
            do {   // one wide poll: lane l watches line l&7 (single RT/iter)
                asm volatile("global_load_dword %0, %1, off sc0 sc1\n\t"
                             "s_waitcnt vmcnt(0)"
                             : "=v"(got) : "v"(pollAddr) : "memory");
            } while (__ballot(got >= tv) != ~0ull);
        }
    }
}

// ---------------- final projection + log_softmax ----------------
__global__ void k_final(const float* __restrict__ hf32, const float* __restrict__ Wph,
                        const float* __restrict__ bp, float* __restrict__ out) {
    __shared__ float red[128];
    int b = blockIdx.x, c = threadIdx.x;
    const float* hr = hf32 + (size_t)b * HH;
    float acc = bp[c];
    for (int k = 0; k < HH; k++) acc += hr[k] * Wph[(size_t)k * NCC + c];
    red[c] = acc;
    __syncthreads();
    for (int st = 64; st > 0; st >>= 1) {
        if (c < st) red[c] = fmaxf(red[c], red[c + st]);
        __syncthreads();
    }
    float m = red[0];
    __syncthreads();
    red[c] = __expf(acc - m);
    __syncthreads();
    for (int st = 64; st > 0; st >>= 1) {
        if (c < st) red[c] += red[c + st];
        __syncthreads();
    }
    out[(size_t)b * NCC + c] = acc - m - __logf(red[0]);
}

extern "C" void kernel_launch(void* const* d_in, const int* in_sizes, int n_in,
                              void* d_out, int out_size, void* d_ws, size_t ws_size,
                              hipStream_t stream) {
    const int*   x   = (const int*)  d_in[0];
    const float* emb = (const float*)d_in[1];
    const float* Wfx = (const float*)d_in[2];
    const float* Wfh = (const float*)d_in[3];
    const float* bf_ = (const float*)d_in[4];
    const float* Wix = (const float*)d_in[5];
    const float* Wih = (const float*)d_in[6];
    const float* bi_ = (const float*)d_in[7];
    const float* Wgx = (const float*)d_in[8];
    const float* Wgh = (const float*)d_in[9];
    const float* bg_ = (const float*)d_in[10];
    const float* Wox = (const float*)d_in[11];
    const float* Woh = (const float*)d_in[12];
    const float* bo_ = (const float*)d_in[13];
    const float* Wph = (const float*)d_in[14];
    const float* bp_ = (const float*)d_in[15];
    float* out = (float*)d_out;

    char* ws = (char*)d_ws;
    unsigned short* WhT   = (unsigned short*)(ws);              // 8 MB
    float*          proj  = (float*)(ws + 8388608);             // 2.02 MB -> ends 10502144
    int*            flags = (int*)(ws + 10502656);              // 64 KB (16384 ints)
    unsigned short* hb0   = (unsigned short*)(ws + 10568192);   // 256 KB
    unsigned short* hb1   = (unsigned short*)(ws + 10830336);   // 256 KB
    float*          hf32  = (float*)(ws + 11092480);            // 512 KB -> ends ~11.6 MB

    k_pre<<<dim3(6672), dim3(256), 0, stream>>>(hb0, flags, Wfh, Wih, Wgh, Woh, WhT,
                                                emb, Wfx, Wix, Wgx, Wox,
                                                bf_, bi_, bg_, bo_, proj);
    k_scan<<<dim3(NWG), dim3(128), 0, stream>>>(x, proj, WhT, hb0, hb1, hf32, flags);
    k_final<<<dim3(128), dim3(128), 0, stream>>>(hf32, Wph, bp_, out);
}

// Round 9
// 1355.566 us; speedup vs baseline: 1.2658x; 1.0097x over previous
//
#include <hip/hip_runtime.h>
#include <hip/hip_bf16.h>

#define BB   128
#define SS   256
#define DD   512
#define HH   1024
#define NCC  128
#define NCLS 129
#define G4   4096   // 4*HH, gate-interleaved: j = hcol*4 + gate (f,i,g,o)
#define NWG  256    // persistent grid size

typedef __attribute__((ext_vector_type(8)))  short  short8;
typedef __attribute__((ext_vector_type(16))) float  f32x16;

static __device__ __forceinline__ float sigm(float x)  { return 1.0f / (1.0f + __expf(-x)); }
static __device__ __forceinline__ float tanh_(float x) { return 1.0f - 2.0f / (__expf(2.0f * x) + 1.0f); }
static __device__ __forceinline__ unsigned short f2b(float v) {
    __hip_bfloat16 h = __float2bfloat16(v);
    return *reinterpret_cast<unsigned short*>(&h);
}
static __device__ __forceinline__ short8 ld16(const unsigned short* p) {
    return *reinterpret_cast<const short8*>(p);
}

// ---------------- fused preamble: init + Wh-conv + proj (independent jobs) ----
// blocks [0,512)      : zero-init h buffer 0 and flag/counter block
// blocks [512,4608)   : Wh -> bf16, transposed, gate-interleaved
// blocks [4608,6672)  : proj[c][j] = emb[c,:] @ Wx[:,hcol] + b
__global__ void k_pre(unsigned short* __restrict__ hb0, int* __restrict__ flags,
                      const float* __restrict__ Wfh, const float* __restrict__ Wih,
                      const float* __restrict__ Wgh, const float* __restrict__ Woh,
                      unsigned short* __restrict__ WhT,
                      const float* __restrict__ emb,
                      const float* __restrict__ Wfx, const float* __restrict__ Wix,
                      const float* __restrict__ Wgx, const float* __restrict__ Wox,
                      const float* __restrict__ bf_, const float* __restrict__ bi_,
                      const float* __restrict__ bg_, const float* __restrict__ bo_,
                      float* __restrict__ proj) {
    __shared__ float t[32][33];
    const int bid = blockIdx.x;
    if (bid < 512) {
        int i = bid * 256 + threadIdx.x;
        if (i < BB * HH) hb0[i] = 0;
        if (i < 16384) flags[i] = 0;
        return;
    }
    if (bid < 4608) {
        int b = bid - 512;
        int bx = b & 31, by = (b >> 5) & 31, g = b >> 10;
        const float* W = (g == 0) ? Wfh : (g == 1) ? Wih : (g == 2) ? Wgh : Woh;
        int h0 = bx * 32, k0 = by * 32;
        int tx = threadIdx.x & 31, ty = threadIdx.x >> 5;
        for (int r = 0; r < 4; r++) {
            int k = ty + r * 8;
            t[k][tx] = W[(size_t)(k0 + k) * HH + h0 + tx];
        }
        __syncthreads();
        for (int r = 0; r < 4; r++) {
            int hl = ty + r * 8;
            int j  = (h0 + hl) * 4 + g;
            WhT[(size_t)j * HH + k0 + tx] = f2b(t[tx][hl]);
        }
        return;
    }
    {
        int b = bid - 4608;
        int c = b >> 4;
        int j = (b & 15) * 256 + threadIdx.x;
        int hcol = j >> 2, g = j & 3;
        const float* Wx = (g == 0) ? Wfx : (g == 1) ? Wix : (g == 2) ? Wgx : Wox;
        const float* bb = (g == 0) ? bf_ : (g == 1) ? bi_ : (g == 2) ? bg_ : bo_;
        float acc = bb[hcol];
        const float* er = emb + (size_t)c * DD;
        for (int d = 0; d < DD; d++) acc += er[d] * Wx[(size_t)d * HH + hcol];
        proj[(size_t)c * G4 + j] = acc;
    }
}

// ---- L2-bypassing 16B load from rolling base (h is cross-XCD dynamic data)
#define LDAB(d, B, L) asm volatile("global_load_dwordx4 %0, %1, off offset:" L " sc0 sc1" \
                                   : "=v"(d) : "v"(B))
// 4 contiguous 1KB loads then advance base 4KB (13-bit offset limit)
#define LD4(A, I) do { \
    LDAB(A[(I)+0], p, "0"); LDAB(A[(I)+1], p, "1024"); \
    LDAB(A[(I)+2], p, "2048"); LDAB(A[(I)+3], p, "3072"); p += 4096; } while (0)
#define LD16(A) do { LD4(A,0); LD4(A,4); LD4(A,8); LD4(A,12); } while (0)

// ---- waitcnt with data-tie so MFMAs can't be scheduled before the wait
#define WAITA(N, A) asm volatile("s_waitcnt vmcnt(" N ")" : \
    "+v"(A[0]),"+v"(A[1]),"+v"(A[2]),"+v"(A[3]),"+v"(A[4]),"+v"(A[5]),"+v"(A[6]),"+v"(A[7]), \
    "+v"(A[8]),"+v"(A[9]),"+v"(A[10]),"+v"(A[11]),"+v"(A[12]),"+v"(A[13]),"+v"(A[14]),"+v"(A[15]))

#define MF16(A, KB) do { \
    acc0 = __builtin_amdgcn_mfma_f32_32x32x16_bf16(A[0],  breg[(KB)+0],  acc0, 0,0,0); \
    acc1 = __builtin_amdgcn_mfma_f32_32x32x16_bf16(A[1],  breg[(KB)+1],  acc1, 0,0,0); \
    acc0 = __builtin_amdgcn_mfma_f32_32x32x16_bf16(A[2],  breg[(KB)+2],  acc0, 0,0,0); \
    acc1 = __builtin_amdgcn_mfma_f32_32x32x16_bf16(A[3],  breg[(KB)+3],  acc1, 0,0,0); \
    acc0 = __builtin_amdgcn_mfma_f32_32x32x16_bf16(A[4],  breg[(KB)+4],  acc0, 0,0,0); \
    acc1 = __builtin_amdgcn_mfma_f32_32x32x16_bf16(A[5],  breg[(KB)+5],  acc1, 0,0,0); \
    acc0 = __builtin_amdgcn_mfma_f32_32x32x16_bf16(A[6],  breg[(KB)+6],  acc0, 0,0,0); \
    acc1 = __builtin_amdgcn_mfma_f32_32x32x16_bf16(A[7],  breg[(KB)+7],  acc1, 0,0,0); \
    acc0 = __builtin_amdgcn_mfma_f32_32x32x16_bf16(A[8],  breg[(KB)+8],  acc0, 0,0,0); \
    acc1 = __builtin_amdgcn_mfma_f32_32x32x16_bf16(A[9],  breg[(KB)+9],  acc1, 0,0,0); \
    acc0 = __builtin_amdgcn_mfma_f32_32x32x16_bf16(A[10], breg[(KB)+10], acc0, 0,0,0); \
    acc1 = __builtin_amdgcn_mfma_f32_32x32x16_bf16(A[11], breg[(KB)+11], acc1, 0,0,0); \
    acc0 = __builtin_amdgcn_mfma_f32_32x32x16_bf16(A[12], breg[(KB)+12], acc0, 0,0,0); \
    acc1 = __builtin_amdgcn_mfma_f32_32x32x16_bf16(A[13], breg[(KB)+13], acc1, 0,0,0); \
    acc0 = __builtin_amdgcn_mfma_f32_32x32x16_bf16(A[14], breg[(KB)+14], acc0, 0,0,0); \
    acc1 = __builtin_amdgcn_mfma_f32_32x32x16_bf16(A[15], breg[(KB)+15], acc1, 0,0,0); \
} while (0)

// 16 gathered proj loads (normal caching); issued BEFORE the poll (r7 lesson),
// completed by the poll's vmcnt(0) (wave 0) or the first WAITA (wave 1).
#define PRLOAD(DSTA, CLSBUF) do { \
    _Pragma("unroll") \
    for (int r = 0; r < 16; r++) { \
        int row = (r & 3) + 8 * (r >> 2) + 4 * half; \
        const float* pa = proj + (size_t)CLSBUF[row] * G4 + jg; \
        asm volatile("global_load_dword %0, %1, off" : "=v"(DSTA[r]) \
                     : "v"((unsigned long long)pa)); \
    } \
} while (0)

// ---------------- persistent LSTM scan ----------------
// 256 WGs x 128 thr (2 waves). WG(mg = wg&3, ng = wg>>2): rows mg*32..+32,
// gate-cols ng*64..+64. WhT slice in registers (full K).
// h stored FRAGMENT-MAJOR: hF[mg][kk][lane][8bf16] so A-loads are 64 x 1KB
// fully-contiguous sector-perfect streams (lane l: m = l&31, k = kk*16+(l>>5)*8+j).
// ONE-HOP barrier per mg-group, arrivals spread over 8 lines (r6-proven):
// atomic_add(+1) on line (ng&7) after the h-store drain. SINGLE-WAVE POLL:
// only wave 0 polls (lane l watches line l&7, ballot-exit); wave 1 waits at the
// trailing __syncthreads(). Halves hot-line read pressure (512 -> 256 pollers)
// so release atomics queue behind half the reads; no extra hop (r3 lesson).
__global__ __launch_bounds__(128, 1)
void k_scan(const int* __restrict__ x, const float* __restrict__ proj,
            const unsigned short* __restrict__ WhT,
            unsigned short* __restrict__ hb0, unsigned short* __restrict__ hb1,
            float* __restrict__ hf32, int* __restrict__ flags) {
    const int wg = blockIdx.x, tid = threadIdx.x;
    const int lane = tid & 63, wv = tid >> 6;
    const int l31 = lane & 31, half = lane >> 5;
    const int mg = wg & 3, ng = wg >> 2;
    const int m0 = mg * 32, n0 = ng * 64;
    const int jg = n0 + wv * 32 + l31;       // this lane's gate-col

    // B fragments: WhT[jg][k], k = kk*16 + half*8 + j  (256 regs)
    short8 breg[64];
    {
        const unsigned short* Bp = WhT + (size_t)jg * HH + half * 8;
        #pragma unroll
        for (int kk = 0; kk < 64; kk++) breg[kk] = ld16(Bp + kk * 16);
    }

    __shared__ float sg[32][68];    // sigmoided gates [row][gate-col]
    __shared__ int   clsS[2][32];   // double-buffered class ids

    float Cst[4] = {0.0f, 0.0f, 0.0f, 0.0f};
    const int urow = tid & 31, uq = tid >> 5;

    if (tid < 32) clsS[0][tid] = x[(size_t)(m0 + tid) * SS];
    __syncthreads();

    // fragment-major bases: hF byte offset = mg*65536 + kk*1024 + lane*16
    const unsigned long long ab0 =
        (unsigned long long)((char*)hb0 + mg * 65536 + lane * 16);
    const unsigned long long ab1 =
        (unsigned long long)((char*)hb1 + mg * 65536 + lane * 16);
    // producer store base: cell = urow + 32*(uq>>1), sub = (uq&1)*8 bytes
    const unsigned long long sb0 = (unsigned long long)((char*)hb0 + mg * 65536
        + ng * 1024 + (urow + ((uq >> 1) << 5)) * 16 + (uq & 1) * 8);
    const unsigned long long sb1 = (unsigned long long)((char*)hb1 + mg * 65536
        + ng * 1024 + (urow + ((uq >> 1) << 5)) * 16 + (uq & 1) * 8);

    // 8 arrival lines per mg-group, 128B-strided (zeroed by k_pre):
    // this WG adds to line (ng&7); wave-0 poll reads line (lane&7).
    const unsigned long long ctrAddr =
        (unsigned long long)(flags + (size_t)(8192 + mg * 256 + (ng & 7) * 32));
    const unsigned long long pollAddr =
        (unsigned long long)(flags + (size_t)(8192 + mg * 256 + (lane & 7) * 32));

    float pr[16];
    PRLOAD(pr, clsS[0]);            // step-0 proj gather (drained by first WAITA)

    for (int s = 0; s < SS; s++) {
        const int cur = s & 1;
        unsigned long long p = cur ? ab1 : ab0;
        const unsigned long long sb = cur ? sb0 : sb1;   // store to the OTHER buffer

        // ---- pipelined A loads: 4 groups x 16 x 1KB contiguous ----
        short8 a0[16], a1[16], a2[16], a3[16];
        LD16(a0);
        LD16(a1);

        f32x16 acc0, acc1;
        #pragma unroll
        for (int r = 0; r < 16; r++) { acc0[r] = 0.0f; acc1[r] = 0.0f; }

        WAITA("16", a0);
        LD16(a2);
        MF16(a0, 0);
        WAITA("16", a1);
        LD16(a3);
        MF16(a1, 16);
        WAITA("16", a2);
        MF16(a2, 32);
        WAITA("0", a3);
        MF16(a3, 48);

        // ---- epilogue: add preloaded proj, sigmoid, stash in LDS ----
        // C/D layout (m74/m101): col = lane&31, row = (r&3) + 8*(r>>2) + 4*(lane>>5)
        #pragma unroll
        for (int r = 0; r < 16; r++) {
            int row = (r & 3) + 8 * (r >> 2) + 4 * half;
            sg[row][wv * 32 + l31] = sigm(acc0[r] + acc1[r] + pr[r]);
        }
        __syncthreads();

        // ---- pointwise: thread owns (row = tid&31, hcols uq*4..+4) ----
        {
            const float rr = (clsS[cur][urow] > 0) ? 1.0f : 0.0f;
            unsigned short hv[4];
            #pragma unroll
            for (int q = 0; q < 4; q++) {
                float4 gq = *reinterpret_cast<const float4*>(&sg[urow][uq * 16 + q * 4]);
                float cn = (gq.z * gq.y + Cst[q] * gq.x) * rr;   // (g*i + C*f)*r
                Cst[q] = cn;
                float hvv = gq.w * tanh_(cn);
                hv[q] = f2b(hvv);
                if (s == SS - 1)
                    hf32[(size_t)(m0 + urow) * HH + ng * 16 + uq * 4 + q] = hvv;
            }
            unsigned long long pk = (unsigned long long)hv[0]
                                  | ((unsigned long long)hv[1] << 16)
                                  | ((unsigned long long)hv[2] << 32)
                                  | ((unsigned long long)hv[3] << 48);
            asm volatile("global_store_dwordx2 %0, %1, off sc0 sc1" :: "v"(sb), "v"(pk) : "memory");
            if (s + 1 < SS && tid < 32)
                clsS[cur ^ 1][tid] = x[(size_t)(m0 + tid) * SS + s + 1];
        }

        // ---- one-hop barrier: drain h-stores, spread atomic arrival,
        //      wave-0-only wide poll, sibling release via syncthreads ----
        if (s < SS - 1) {
            asm volatile("s_waitcnt vmcnt(0)" ::: "memory");   // h-store drained at L3
            __syncthreads();
            if (tid == 0) {
                int one = 1;
                asm volatile("global_atomic_add %0, %1, off"
                             :: "v"(ctrAddr), "v"(one) : "memory");
            }
            PRLOAD(pr, clsS[cur ^ 1]);     // next step's proj gather (both waves)
            if (wv == 0) {
                const int tv = (s + 1) << 3;   // 8 WGs per arrival line
                int got;
                do {   // wide poll: lane l watches line l&7 (single RT/iter)
                    asm volatile("global_load_dword %0, %1, off sc0 sc1\n\t"
                                 "s_waitcnt vmcnt(0)"
                                 : "=v"(got) : "v"(pollAddr) : "memory");
                } while (__ballot(got >= tv) != ~0ull);
            }
            __syncthreads();               // releases wave 1 (its pr stays in flight)
        }
    }
}

// ---------------- final projection + log_softmax ----------------
__global__ void k_final(const float* __restrict__ hf32, const float* __restrict__ Wph,
                        const float* __restrict__ bp, float* __restrict__ out) {
    __shared__ float red[128];
    int b = blockIdx.x, c = threadIdx.x;
    const float* hr = hf32 + (size_t)b * HH;
    float acc = bp[c];
    for (int k = 0; k < HH; k++) acc += hr[k] * Wph[(size_t)k * NCC + c];
    red[c] = acc;
    __syncthreads();
    for (int st = 64; st > 0; st >>= 1) {
        if (c < st) red[c] = fmaxf(red[c], red[c + st]);
        __syncthreads();
    }
    float m = red[0];
    __syncthreads();
    red[c] = __expf(acc - m);
    __syncthreads();
    for (int st = 64; st > 0; st >>= 1) {
        if (c < st) red[c] += red[c + st];
        __syncthreads();
    }
    out[(size_t)b * NCC + c] = acc - m - __logf(red[0]);
}

extern "C" void kernel_launch(void* const* d_in, const int* in_sizes, int n_in,
                              void* d_out, int out_size, void* d_ws, size_t ws_size,
                              hipStream_t stream) {
    const int*   x   = (const int*)  d_in[0];
    const float* emb = (const float*)d_in[1];
    const float* Wfx = (const float*)d_in[2];
    const float* Wfh = (const float*)d_in[3];
    const float* bf_ = (const float*)d_in[4];
    const float* Wix = (const float*)d_in[5];
    const float* Wih = (const float*)d_in[6];
    const float* bi_ = (const float*)d_in[7];
    const float* Wgx = (const float*)d_in[8];
    const float* Wgh = (const float*)d_in[9];
    const float* bg_ = (const float*)d_in[10];
    const float* Wox = (const float*)d_in[11];
    const float* Woh = (const float*)d_in[12];
    const float* bo_ = (const float*)d_in[13];
    const float* Wph = (const float*)d_in[14];
    const float* bp_ = (const float*)d_in[15];
    float* out = (float*)d_out;

    char* ws = (char*)d_ws;
    unsigned short* WhT   = (unsigned short*)(ws);              // 8 MB
    float*          proj  = (float*)(ws + 8388608);             // 2.02 MB -> ends 10502144
    int*            flags = (int*)(ws + 10502656);              // 64 KB (16384 ints)
    unsigned short* hb0   = (unsigned short*)(ws + 10568192);   // 256 KB
    unsigned short* hb1   = (unsigned short*)(ws + 10830336);   // 256 KB
    float*          hf32  = (float*)(ws + 11092480);            // 512 KB -> ends ~11.6 MB

    k_pre<<<dim3(6672), dim3(256), 0, stream>>>(hb0, flags, Wfh, Wih, Wgh, Woh, WhT,
                                                emb, Wfx, Wix, Wgx, Wox,
                                                bf_, bi_, bg_, bo_, proj);
    k_scan<<<dim3(NWG), dim3(128), 0, stream>>>(x, proj, WhT, hb0, hb1, hf32, flags);
    k_final<<<dim3(128), dim3(128), 0, stream>>>(hf32, Wph, bp_, out);
}

// Round 10
// 1297.548 us; speedup vs baseline: 1.3224x; 1.0447x over previous
//
#include <hip/hip_runtime.h>
#include <hip/hip_bf16.h>

#define BB   128
#define SS   256
#define DD   512
#define HH   1024
#define NCC  128
#define NCLS 129
#define G4   4096   // 4*HH, gate-interleaved: j = hcol*4 + gate (f,i,g,o)
#define NWG  256    // persistent grid size

typedef __attribute__((ext_vector_type(8)))  short  short8;
typedef __attribute__((ext_vector_type(16))) float  f32x16;

static __device__ __forceinline__ float sigm(float x)  { return 1.0f / (1.0f + __expf(-x)); }
static __device__ __forceinline__ float tanh_(float x) { return 1.0f - 2.0f / (__expf(2.0f * x) + 1.0f); }
static __device__ __forceinline__ unsigned short f2b(float v) {
    __hip_bfloat16 h = __float2bfloat16(v);
    return *reinterpret_cast<unsigned short*>(&h);
}
static __device__ __forceinline__ short8 ld16(const unsigned short* p) {
    return *reinterpret_cast<const short8*>(p);
}

// ---------------- fused preamble: init + Wh-conv + proj (independent jobs) ----
// blocks [0,512)      : zero-init h buffer 0 and flag/counter block
// blocks [512,4608)   : Wh -> bf16, transposed, gate-interleaved
// blocks [4608,6672)  : proj[c][j] = emb[c,:] @ Wx[:,hcol] + b
__global__ void k_pre(unsigned short* __restrict__ hb0, int* __restrict__ flags,
                      const float* __restrict__ Wfh, const float* __restrict__ Wih,
                      const float* __restrict__ Wgh, const float* __restrict__ Woh,
                      unsigned short* __restrict__ WhT,
                      const float* __restrict__ emb,
                      const float* __restrict__ Wfx, const float* __restrict__ Wix,
                      const float* __restrict__ Wgx, const float* __restrict__ Wox,
                      const float* __restrict__ bf_, const float* __restrict__ bi_,
                      const float* __restrict__ bg_, const float* __restrict__ bo_,
                      float* __restrict__ proj) {
    __shared__ float t[32][33];
    const int bid = blockIdx.x;
    if (bid < 512) {
        int i = bid * 256 + threadIdx.x;
        if (i < BB * HH) hb0[i] = 0;
        if (i < 16384) flags[i] = 0;
        return;
    }
    if (bid < 4608) {
        int b = bid - 512;
        int bx = b & 31, by = (b >> 5) & 31, g = b >> 10;
        const float* W = (g == 0) ? Wfh : (g == 1) ? Wih : (g == 2) ? Wgh : Woh;
        int h0 = bx * 32, k0 = by * 32;
        int tx = threadIdx.x & 31, ty = threadIdx.x >> 5;
        for (int r = 0; r < 4; r++) {
            int k = ty + r * 8;
            t[k][tx] = W[(size_t)(k0 + k) * HH + h0 + tx];
        }
        __syncthreads();
        for (int r = 0; r < 4; r++) {
            int hl = ty + r * 8;
            int j  = (h0 + hl) * 4 + g;
            WhT[(size_t)j * HH + k0 + tx] = f2b(t[tx][hl]);
        }
        return;
    }
    {
        int b = bid - 4608;
        int c = b >> 4;
        int j = (b & 15) * 256 + threadIdx.x;
        int hcol = j >> 2, g = j & 3;
        const float* Wx = (g == 0) ? Wfx : (g == 1) ? Wix : (g == 2) ? Wgx : Wox;
        const float* bb = (g == 0) ? bf_ : (g == 1) ? bi_ : (g == 2) ? bg_ : bo_;
        float acc = bb[hcol];
        const float* er = emb + (size_t)c * DD;
        for (int d = 0; d < DD; d++) acc += er[d] * Wx[(size_t)d * HH + hcol];
        proj[(size_t)c * G4 + j] = acc;
    }
}

// ---- L2-bypassing 16B load from rolling base (h is cross-XCD dynamic data)
#define LDAB(d, B, L) asm volatile("global_load_dwordx4 %0, %1, off offset:" L " sc0 sc1" \
                                   : "=v"(d) : "v"(B))
// 4 contiguous 1KB loads then advance base 4KB (13-bit offset limit)
#define LD4(A, I) do { \
    LDAB(A[(I)+0], p, "0"); LDAB(A[(I)+1], p, "1024"); \
    LDAB(A[(I)+2], p, "2048"); LDAB(A[(I)+3], p, "3072"); p += 4096; } while (0)
#define LD16(A) do { LD4(A,0); LD4(A,4); LD4(A,8); LD4(A,12); } while (0)

// ---- waitcnt with data-tie so MFMAs can't be scheduled before the wait
#define WAITA(N, A) asm volatile("s_waitcnt vmcnt(" N ")" : \
    "+v"(A[0]),"+v"(A[1]),"+v"(A[2]),"+v"(A[3]),"+v"(A[4]),"+v"(A[5]),"+v"(A[6]),"+v"(A[7]), \
    "+v"(A[8]),"+v"(A[9]),"+v"(A[10]),"+v"(A[11]),"+v"(A[12]),"+v"(A[13]),"+v"(A[14]),"+v"(A[15]))

#define MF16(A, KB) do { \
    acc0 = __builtin_amdgcn_mfma_f32_32x32x16_bf16(A[0],  breg[(KB)+0],  acc0, 0,0,0); \
    acc1 = __builtin_amdgcn_mfma_f32_32x32x16_bf16(A[1],  breg[(KB)+1],  acc1, 0,0,0); \
    acc0 = __builtin_amdgcn_mfma_f32_32x32x16_bf16(A[2],  breg[(KB)+2],  acc0, 0,0,0); \
    acc1 = __builtin_amdgcn_mfma_f32_32x32x16_bf16(A[3],  breg[(KB)+3],  acc1, 0,0,0); \
    acc0 = __builtin_amdgcn_mfma_f32_32x32x16_bf16(A[4],  breg[(KB)+4],  acc0, 0,0,0); \
    acc1 = __builtin_amdgcn_mfma_f32_32x32x16_bf16(A[5],  breg[(KB)+5],  acc1, 0,0,0); \
    acc0 = __builtin_amdgcn_mfma_f32_32x32x16_bf16(A[6],  breg[(KB)+6],  acc0, 0,0,0); \
    acc1 = __builtin_amdgcn_mfma_f32_32x32x16_bf16(A[7],  breg[(KB)+7],  acc1, 0,0,0); \
    acc0 = __builtin_amdgcn_mfma_f32_32x32x16_bf16(A[8],  breg[(KB)+8],  acc0, 0,0,0); \
    acc1 = __builtin_amdgcn_mfma_f32_32x32x16_bf16(A[9],  breg[(KB)+9],  acc1, 0,0,0); \
    acc0 = __builtin_amdgcn_mfma_f32_32x32x16_bf16(A[10], breg[(KB)+10], acc0, 0,0,0); \
    acc1 = __builtin_amdgcn_mfma_f32_32x32x16_bf16(A[11], breg[(KB)+11], acc1, 0,0,0); \
    acc0 = __builtin_amdgcn_mfma_f32_32x32x16_bf16(A[12], breg[(KB)+12], acc0, 0,0,0); \
    acc1 = __builtin_amdgcn_mfma_f32_32x32x16_bf16(A[13], breg[(KB)+13], acc1, 0,0,0); \
    acc0 = __builtin_amdgcn_mfma_f32_32x32x16_bf16(A[14], breg[(KB)+14], acc0, 0,0,0); \
    acc1 = __builtin_amdgcn_mfma_f32_32x32x16_bf16(A[15], breg[(KB)+15], acc1, 0,0,0); \
} while (0)

// 16 gathered proj loads (normal caching); issued BEFORE the poll (r7 lesson),
// completed by the poll's vmcnt(0).
#define PRLOAD(DSTA, CLSBUF) do { \
    _Pragma("unroll") \
    for (int r = 0; r < 16; r++) { \
        int row = (r & 3) + 8 * (r >> 2) + 4 * half; \
        const float* pa = proj + (size_t)CLSBUF[row] * G4 + jg; \
        asm volatile("global_load_dword %0, %1, off" : "=v"(DSTA[r]) \
                     : "v"((unsigned long long)pa)); \
    } \
} while (0)

// ---------------- persistent LSTM scan ----------------
// 256 WGs x 128 thr (2 waves), but the waves are FULLY DECOUPLED: wave wv of
// WG(mg,ng) owns gate-cols for hcols ng*16+wv*8..+8 end to end -- MFMA, sg
// epilogue (cols wv*32..+32), pointwise (uq = 2wv..2wv+1 reads only those
// cols), and h-stores (its k-half of fragment ng). The r6 kernel's two
// __syncthreads per step only coupled the waves' arrival chains; here they are
// replaced by an in-wave s_waitcnt lgkmcnt(0) (cross-LANE sg access only).
// Per-wave class-id buffer clsW[wv] removes the last cross-wave dependency.
// ONE-HOP barrier per mg-group, arrivals spread over 8 lines (r6-proven), now
// 128 per group: lane 0 of EACH WAVE posts +1 after its own vmcnt(0) drain;
// target 16/line. Wide poll unchanged (lane l watches line l&7, ballot-exit).
// 2-slot h double-buffer safety: a wave posts s+1 only after its step-s A-reads
// completed (WAITA("0") precedes pointwise), so skew stays < 2 steps.
__global__ __launch_bounds__(128, 1)
void k_scan(const int* __restrict__ x, const float* __restrict__ proj,
            const unsigned short* __restrict__ WhT,
            unsigned short* __restrict__ hb0, unsigned short* __restrict__ hb1,
            float* __restrict__ hf32, int* __restrict__ flags) {
    const int wg = blockIdx.x, tid = threadIdx.x;
    const int lane = tid & 63, wv = tid >> 6;
    const int l31 = lane & 31, half = lane >> 5;
    const int mg = wg & 3, ng = wg >> 2;
    const int m0 = mg * 32, n0 = ng * 64;
    const int jg = n0 + wv * 32 + l31;       // this lane's gate-col

    // B fragments: WhT[jg][k], k = kk*16 + half*8 + j  (256 regs)
    short8 breg[64];
    {
        const unsigned short* Bp = WhT + (size_t)jg * HH + half * 8;
        #pragma unroll
        for (int kk = 0; kk < 64; kk++) breg[kk] = ld16(Bp + kk * 16);
    }

    __shared__ float sg[32][68];      // sigmoided gates [row][gate-col]; cols
                                      // 0..31 wave0-private, 32..63 wave1-private
    __shared__ int   clsW[2][2][32];  // per-wave double-buffered class ids

    float Cst[4] = {0.0f, 0.0f, 0.0f, 0.0f};
    const int urow = tid & 31, uq = tid >> 5;   // uq in {2wv, 2wv+1}

    if (lane < 32) clsW[wv][0][lane] = x[(size_t)(m0 + lane) * SS];
    // no barrier: clsW[wv] is wave-private; lgkmcnt(0) below orders it

    // fragment-major bases: hF byte offset = mg*65536 + kk*1024 + lane*16
    const unsigned long long ab0 =
        (unsigned long long)((char*)hb0 + mg * 65536 + lane * 16);
    const unsigned long long ab1 =
        (unsigned long long)((char*)hb1 + mg * 65536 + lane * 16);
    // producer store base: lane_c = urow + 32*(uq>>1), sub = (uq&1)*8 bytes
    const unsigned long long sb0 = (unsigned long long)((char*)hb0 + mg * 65536
        + ng * 1024 + (urow + ((uq >> 1) << 5)) * 16 + (uq & 1) * 8);
    const unsigned long long sb1 = (unsigned long long)((char*)hb1 + mg * 65536
        + ng * 1024 + (urow + ((uq >> 1) << 5)) * 16 + (uq & 1) * 8);

    // 8 arrival lines per mg-group, 128B-strided (zeroed by k_pre):
    // each WAVE adds to line (ng&7); poll reads line (lane&7).
    const unsigned long long ctrAddr =
        (unsigned long long)(flags + (size_t)(8192 + mg * 256 + (ng & 7) * 32));
    const unsigned long long pollAddr =
        (unsigned long long)(flags + (size_t)(8192 + mg * 256 + (lane & 7) * 32));

    float pr[16];
    PRLOAD(pr, clsW[wv][0]);        // step-0 proj gather (drained by first WAITA)

    for (int s = 0; s < SS; s++) {
        const int cur = s & 1;
        unsigned long long p = cur ? ab1 : ab0;
        const unsigned long long sb = cur ? sb0 : sb1;   // store to the OTHER buffer

        // ---- pipelined A loads: 4 groups x 16 x 1KB contiguous ----
        short8 a0[16], a1[16], a2[16], a3[16];
        LD16(a0);
        LD16(a1);

        f32x16 acc0, acc1;
        #pragma unroll
        for (int r = 0; r < 16; r++) { acc0[r] = 0.0f; acc1[r] = 0.0f; }

        WAITA("16", a0);
        LD16(a2);
        MF16(a0, 0);
        WAITA("16", a1);
        LD16(a3);
        MF16(a1, 16);
        WAITA("16", a2);
        MF16(a2, 32);
        WAITA("0", a3);
        MF16(a3, 48);

        // ---- epilogue: add preloaded proj, sigmoid, stash in own sg cols ----
        // C/D layout (m74/m101): col = lane&31, row = (r&3) + 8*(r>>2) + 4*(lane>>5)
        #pragma unroll
        for (int r = 0; r < 16; r++) {
            int row = (r & 3) + 8 * (r >> 2) + 4 * half;
            sg[row][wv * 32 + l31] = sigm(acc0[r] + acc1[r] + pr[r]);
        }
        // in-wave cross-lane handoff: wait LDS writes, no inter-wave barrier
        asm volatile("s_waitcnt lgkmcnt(0)" ::: "memory");

        // ---- pointwise: thread owns (row = tid&31, hcols uq*4..+4) ----
        {
            const float rr = (clsW[wv][cur][urow] > 0) ? 1.0f : 0.0f;
            unsigned short hv[4];
            #pragma unroll
            for (int q = 0; q < 4; q++) {
                float4 gq = *reinterpret_cast<const float4*>(&sg[urow][uq * 16 + q * 4]);
                float cn = (gq.z * gq.y + Cst[q] * gq.x) * rr;   // (g*i + C*f)*r
                Cst[q] = cn;
                float hvv = gq.w * tanh_(cn);
                hv[q] = f2b(hvv);
                if (s == SS - 1)
                    hf32[(size_t)(m0 + urow) * HH + ng * 16 + uq * 4 + q] = hvv;
            }
            unsigned long long pk = (unsigned long long)hv[0]
                                  | ((unsigned long long)hv[1] << 16)
                                  | ((unsigned long long)hv[2] << 32)
                                  | ((unsigned long long)hv[3] << 48);
            asm volatile("global_store_dwordx2 %0, %1, off sc0 sc1" :: "v"(sb), "v"(pk) : "memory");
            if (s + 1 < SS && lane < 32)
                clsW[wv][cur ^ 1][lane] = x[(size_t)(m0 + lane) * SS + s + 1];
        }

        // ---- per-wave barrier leg: drain own h-stores, post arrival, poll ----
        if (s < SS - 1) {
            asm volatile("s_waitcnt vmcnt(0)" ::: "memory");   // own stores at L3
            if (lane == 0) {
                int one = 1;
                asm volatile("global_atomic_add %0, %1, off"
                             :: "v"(ctrAddr), "v"(one) : "memory");
            }
            PRLOAD(pr, clsW[wv][cur ^ 1]); // next step's proj gather, rides the poll
            const int tv = (s + 1) << 4;   // 16 waves per arrival line
            int got;
            do {   // one wide poll: lane l watches line l&7 (single RT/iter)
                asm volatile("global_load_dword %0, %1, off sc0 sc1\n\t"
                             "s_waitcnt vmcnt(0)"
                             : "=v"(got) : "v"(pollAddr) : "memory");
            } while (__ballot(got >= tv) != ~0ull);
        }
    }
}

// ---------------- final projection + log_softmax ----------------
__global__ void k_final(const float* __restrict__ hf32, const float* __restrict__ Wph,
                        const float* __restrict__ bp, float* __restrict__ out) {
    __shared__ float red[128];
    int b = blockIdx.x, c = threadIdx.x;
    const float* hr = hf32 + (size_t)b * HH;
    float acc = bp[c];
    for (int k = 0; k < HH; k++) acc += hr[k] * Wph[(size_t)k * NCC + c];
    red[c] = acc;
    __syncthreads();
    for (int st = 64; st > 0; st >>= 1) {
        if (c < st) red[c] = fmaxf(red[c], red[c + st]);
        __syncthreads();
    }
    float m = red[0];
    __syncthreads();
    red[c] = __expf(acc - m);
    __syncthreads();
    for (int st = 64; st > 0; st >>= 1) {
        if (c < st) red[c] += red[c + st];
        __syncthreads();
    }
    out[(size_t)b * NCC + c] = acc - m - __logf(red[0]);
}

extern "C" void kernel_launch(void* const* d_in, const int* in_sizes, int n_in,
                              void* d_out, int out_size, void* d_ws, size_t ws_size,
                              hipStream_t stream) {
    const int*   x   = (const int*)  d_in[0];
    const float* emb = (const float*)d_in[1];
    const float* Wfx = (const float*)d_in[2];
    const float* Wfh = (const float*)d_in[3];
    const float* bf_ = (const float*)d_in[4];
    const float* Wix = (const float*)d_in[5];
    const float* Wih = (const float*)d_in[6];
    const float* bi_ = (const float*)d_in[7];
    const float* Wgx = (const float*)d_in[8];
    const float* Wgh = (const float*)d_in[9];
    const float* bg_ = (const float*)d_in[10];
    const float* Wox = (const float*)d_in[11];
    const float* Woh = (const float*)d_in[12];
    const float* bo_ = (const float*)d_in[13];
    const float* Wph = (const float*)d_in[14];
    const float* bp_ = (const float*)d_in[15];
    float* out = (float*)d_out;

    char* ws = (char*)d_ws;
    unsigned short* WhT   = (unsigned short*)(ws);              // 8 MB
    float*          proj  = (float*)(ws + 8388608);             // 2.02 MB -> ends 10502144
    int*            flags = (int*)(ws + 10502656);              // 64 KB (16384 ints)
    unsigned short* hb0   = (unsigned short*)(ws + 10568192);   // 256 KB
    unsigned short* hb1   = (unsigned short*)(ws + 10830336);   // 256 KB
    float*          hf32  = (float*)(ws + 11092480);            // 512 KB -> ends ~11.6 MB

    k_pre<<<dim3(6672), dim3(256), 0, stream>>>(hb0, flags, Wfh, Wih, Wgh, Woh, WhT,
                                                emb, Wfx, Wix, Wgx, Wox,
                                                bf_, bi_, bg_, bo_, proj);
    k_scan<<<dim3(NWG), dim3(128), 0, stream>>>(x, proj, WhT, hb0, hb1, hf32, flags);
    k_final<<<dim3(128), dim3(128), 0, stream>>>(hf32, Wph, bp_, out);
}

// Round 11
// 1277.192 us; speedup vs baseline: 1.3435x; 1.0159x over previous
//
#include <hip/hip_runtime.h>
#include <hip/hip_bf16.h>

#define BB   128
#define SS   256
#define DD   512
#define HH   1024
#define NCC  128
#define NCLS 129
#define G4   4096   // 4*HH, gate-interleaved: j = hcol*4 + gate (f,i,g,o)
#define NWG  256    // persistent grid size

typedef __attribute__((ext_vector_type(8)))  short  short8;
typedef __attribute__((ext_vector_type(16))) float  f32x16;

static __device__ __forceinline__ float sigm(float x)  { return 1.0f / (1.0f + __expf(-x)); }
static __device__ __forceinline__ float tanh_(float x) { return 1.0f - 2.0f / (__expf(2.0f * x) + 1.0f); }
static __device__ __forceinline__ unsigned short f2b(float v) {
    __hip_bfloat16 h = __float2bfloat16(v);
    return *reinterpret_cast<unsigned short*>(&h);
}
static __device__ __forceinline__ short8 ld16(const unsigned short* p) {
    return *reinterpret_cast<const short8*>(p);
}

// ---------------- fused preamble: init + Wh-conv + proj (independent jobs) ----
// blocks [0,512)      : zero-init h buffer 0 and flag/counter block
// blocks [512,4608)   : Wh -> bf16, transposed, gate-interleaved
// blocks [4608,4864)  : proj, CLASS-TILED: block = (gate, 16-hcol tile), all
//   129 classes. Wx tile staged once in LDS (32KB) -> Wx read ONCE total
//   (8MB) instead of once per class (1GB); emb rows are float4 broadcasts.
__global__ void k_pre(unsigned short* __restrict__ hb0, int* __restrict__ flags,
                      const float* __restrict__ Wfh, const float* __restrict__ Wih,
                      const float* __restrict__ Wgh, const float* __restrict__ Woh,
                      unsigned short* __restrict__ WhT,
                      const float* __restrict__ emb,
                      const float* __restrict__ Wfx, const float* __restrict__ Wix,
                      const float* __restrict__ Wgx, const float* __restrict__ Wox,
                      const float* __restrict__ bf_, const float* __restrict__ bi_,
                      const float* __restrict__ bg_, const float* __restrict__ bo_,
                      float* __restrict__ proj) {
    __shared__ float  t[32][33];
    __shared__ float4 wxs[128][16];   // [d/4][hcol] tile of Wx, 32KB
    const int bid = blockIdx.x;
    if (bid < 512) {
        int i = bid * 256 + threadIdx.x;
        if (i < BB * HH) hb0[i] = 0;
        if (i < 16384) flags[i] = 0;
        return;
    }
    if (bid < 4608) {
        int b = bid - 512;
        int bx = b & 31, by = (b >> 5) & 31, g = b >> 10;
        const float* W = (g == 0) ? Wfh : (g == 1) ? Wih : (g == 2) ? Wgh : Woh;
        int h0 = bx * 32, k0 = by * 32;
        int tx = threadIdx.x & 31, ty = threadIdx.x >> 5;
        for (int r = 0; r < 4; r++) {
            int k = ty + r * 8;
            t[k][tx] = W[(size_t)(k0 + k) * HH + h0 + tx];
        }
        __syncthreads();
        for (int r = 0; r < 4; r++) {
            int hl = ty + r * 8;
            int j  = (h0 + hl) * 4 + g;
            WhT[(size_t)j * HH + k0 + tx] = f2b(t[tx][hl]);
        }
        return;
    }
    {
        // proj: pb = bid-4608 in [0,256): g = pb&3, tile = pb>>2, hcol0 = tile*16
        int pb = bid - 4608;
        int g = pb & 3, hcol0 = (pb >> 2) * 16;
        const float* Wx = (g == 0) ? Wfx : (g == 1) ? Wix : (g == 2) ? Wgx : Wox;
        const float* bb = (g == 0) ? bf_ : (g == 1) ? bi_ : (g == 2) ? bg_ : bo_;
        // stage Wx[:, hcol0..+16] into LDS as float4 over d
        for (int i = threadIdx.x; i < 2048; i += 256) {
            int d4 = i >> 4, hc = i & 15;
            const float* w = Wx + (size_t)(d4 * 4) * HH + hcol0 + hc;
            wxs[d4][hc] = make_float4(w[0], w[HH], w[2 * HH], w[3 * HH]);
        }
        __syncthreads();
        int hc = threadIdx.x & 15, c0 = threadIdx.x >> 4;
        float bias = bb[hcol0 + hc];
        for (int c = c0; c < NCLS; c += 16) {
            const float4* er = reinterpret_cast<const float4*>(emb + (size_t)c * DD);
            float acc = bias;
            #pragma unroll 8
            for (int d4 = 0; d4 < 128; d4++) {
                float4 e = er[d4];          // broadcast across the 16-thread group
                float4 w = wxs[d4][hc];
                acc += e.x * w.x + e.y * w.y + e.z * w.z + e.w * w.w;
            }
            proj[(size_t)c * G4 + (hcol0 + hc) * 4 + g] = acc;
        }
    }
}

// ---- L2-bypassing 16B load from rolling base (h is cross-XCD dynamic data)
#define LDAB(d, B, L) asm volatile("global_load_dwordx4 %0, %1, off offset:" L " sc0 sc1" \
                                   : "=v"(d) : "v"(B))
// 4 contiguous 1KB loads then advance base 4KB (13-bit offset limit)
#define LD4(A, I) do { \
    LDAB(A[(I)+0], p, "0"); LDAB(A[(I)+1], p, "1024"); \
    LDAB(A[(I)+2], p, "2048"); LDAB(A[(I)+3], p, "3072"); p += 4096; } while (0)
#define LD16(A) do { LD4(A,0); LD4(A,4); LD4(A,8); LD4(A,12); } while (0)

// ---- waitcnt with data-tie so MFMAs can't be scheduled before the wait
#define WAITA(N, A) asm volatile("s_waitcnt vmcnt(" N ")" : \
    "+v"(A[0]),"+v"(A[1]),"+v"(A[2]),"+v"(A[3]),"+v"(A[4]),"+v"(A[5]),"+v"(A[6]),"+v"(A[7]), \
    "+v"(A[8]),"+v"(A[9]),"+v"(A[10]),"+v"(A[11]),"+v"(A[12]),"+v"(A[13]),"+v"(A[14]),"+v"(A[15]))

#define MF16(A, KB) do { \
    acc0 = __builtin_amdgcn_mfma_f32_32x32x16_bf16(A[0],  breg[(KB)+0],  acc0, 0,0,0); \
    acc1 = __builtin_amdgcn_mfma_f32_32x32x16_bf16(A[1],  breg[(KB)+1],  acc1, 0,0,0); \
    acc0 = __builtin_amdgcn_mfma_f32_32x32x16_bf16(A[2],  breg[(KB)+2],  acc0, 0,0,0); \
    acc1 = __builtin_amdgcn_mfma_f32_32x32x16_bf16(A[3],  breg[(KB)+3],  acc1, 0,0,0); \
    acc0 = __builtin_amdgcn_mfma_f32_32x32x16_bf16(A[4],  breg[(KB)+4],  acc0, 0,0,0); \
    acc1 = __builtin_amdgcn_mfma_f32_32x32x16_bf16(A[5],  breg[(KB)+5],  acc1, 0,0,0); \
    acc0 = __builtin_amdgcn_mfma_f32_32x32x16_bf16(A[6],  breg[(KB)+6],  acc0, 0,0,0); \
    acc1 = __builtin_amdgcn_mfma_f32_32x32x16_bf16(A[7],  breg[(KB)+7],  acc1, 0,0,0); \
    acc0 = __builtin_amdgcn_mfma_f32_32x32x16_bf16(A[8],  breg[(KB)+8],  acc0, 0,0,0); \
    acc1 = __builtin_amdgcn_mfma_f32_32x32x16_bf16(A[9],  breg[(KB)+9],  acc1, 0,0,0); \
    acc0 = __builtin_amdgcn_mfma_f32_32x32x16_bf16(A[10], breg[(KB)+10], acc0, 0,0,0); \
    acc1 = __builtin_amdgcn_mfma_f32_32x32x16_bf16(A[11], breg[(KB)+11], acc1, 0,0,0); \
    acc0 = __builtin_amdgcn_mfma_f32_32x32x16_bf16(A[12], breg[(KB)+12], acc0, 0,0,0); \
    acc1 = __builtin_amdgcn_mfma_f32_32x32x16_bf16(A[13], breg[(KB)+13], acc1, 0,0,0); \
    acc0 = __builtin_amdgcn_mfma_f32_32x32x16_bf16(A[14], breg[(KB)+14], acc0, 0,0,0); \
    acc1 = __builtin_amdgcn_mfma_f32_32x32x16_bf16(A[15], breg[(KB)+15], acc1, 0,0,0); \
} while (0)

// 16 gathered proj loads (normal caching); issued BEFORE the poll (r7 lesson),
// completed by the poll's vmcnt(0).
#define PRLOAD(DSTA, CLSBUF) do { \
    _Pragma("unroll") \
    for (int r = 0; r < 16; r++) { \
        int row = (r & 3) + 8 * (r >> 2) + 4 * half; \
        const float* pa = proj + (size_t)CLSBUF[row] * G4 + jg; \
        asm volatile("global_load_dword %0, %1, off" : "=v"(DSTA[r]) \
                     : "v"((unsigned long long)pa)); \
    } \
} while (0)

// ---------------- persistent LSTM scan (r10 winner, byte-identical) ----------
// 256 WGs x 128 thr (2 waves), waves FULLY DECOUPLED: wave wv of WG(mg,ng)
// owns gate-cols for hcols ng*16+wv*8..+8 end to end. Per-step __syncthreads
// replaced by in-wave s_waitcnt lgkmcnt(0); per-wave clsW buffers.
// ONE-HOP barrier per mg-group, arrivals spread over 8 lines, 128 arrivals
// per group (lane 0 of each wave posts after its own vmcnt(0) drain).
__global__ __launch_bounds__(128, 1)
void k_scan(const int* __restrict__ x, const float* __restrict__ proj,
            const unsigned short* __restrict__ WhT,
            unsigned short* __restrict__ hb0, unsigned short* __restrict__ hb1,
            float* __restrict__ hf32, int* __restrict__ flags) {
    const int wg = blockIdx.x, tid = threadIdx.x;
    const int lane = tid & 63, wv = tid >> 6;
    const int l31 = lane & 31, half = lane >> 5;
    const int mg = wg & 3, ng = wg >> 2;
    const int m0 = mg * 32, n0 = ng * 64;
    const int jg = n0 + wv * 32 + l31;       // this lane's gate-col

    // B fragments: WhT[jg][k], k = kk*16 + half*8 + j  (256 regs)
    short8 breg[64];
    {
        const unsigned short* Bp = WhT + (size_t)jg * HH + half * 8;
        #pragma unroll
        for (int kk = 0; kk < 64; kk++) breg[kk] = ld16(Bp + kk * 16);
    }

    __shared__ float sg[32][68];      // sigmoided gates [row][gate-col]; cols
                                      // 0..31 wave0-private, 32..63 wave1-private
    __shared__ int   clsW[2][2][32];  // per-wave double-buffered class ids

    float Cst[4] = {0.0f, 0.0f, 0.0f, 0.0f};
    const int urow = tid & 31, uq = tid >> 5;   // uq in {2wv, 2wv+1}

    if (lane < 32) clsW[wv][0][lane] = x[(size_t)(m0 + lane) * SS];
    // no barrier: clsW[wv] is wave-private; lgkmcnt(0) below orders it

    // fragment-major bases: hF byte offset = mg*65536 + kk*1024 + lane*16
    const unsigned long long ab0 =
        (unsigned long long)((char*)hb0 + mg * 65536 + lane * 16);
    const unsigned long long ab1 =
        (unsigned long long)((char*)hb1 + mg * 65536 + lane * 16);
    // producer store base: lane_c = urow + 32*(uq>>1), sub = (uq&1)*8 bytes
    const unsigned long long sb0 = (unsigned long long)((char*)hb0 + mg * 65536
        + ng * 1024 + (urow + ((uq >> 1) << 5)) * 16 + (uq & 1) * 8);
    const unsigned long long sb1 = (unsigned long long)((char*)hb1 + mg * 65536
        + ng * 1024 + (urow + ((uq >> 1) << 5)) * 16 + (uq & 1) * 8);

    // 8 arrival lines per mg-group, 128B-strided (zeroed by k_pre):
    // each WAVE adds to line (ng&7); poll reads line (lane&7).
    const unsigned long long ctrAddr =
        (unsigned long long)(flags + (size_t)(8192 + mg * 256 + (ng & 7) * 32));
    const unsigned long long pollAddr =
        (unsigned long long)(flags + (size_t)(8192 + mg * 256 + (lane & 7) * 32));

    float pr[16];
    PRLOAD(pr, clsW[wv][0]);        // step-0 proj gather (drained by first WAITA)

    for (int s = 0; s < SS; s++) {
        const int cur = s & 1;
        unsigned long long p = cur ? ab1 : ab0;
        const unsigned long long sb = cur ? sb0 : sb1;   // store to the OTHER buffer

        // ---- pipelined A loads: 4 groups x 16 x 1KB contiguous ----
        short8 a0[16], a1[16], a2[16], a3[16];
        LD16(a0);
        LD16(a1);

        f32x16 acc0, acc1;
        #pragma unroll
        for (int r = 0; r < 16; r++) { acc0[r] = 0.0f; acc1[r] = 0.0f; }

        WAITA("16", a0);
        LD16(a2);
        MF16(a0, 0);
        WAITA("16", a1);
        LD16(a3);
        MF16(a1, 16);
        WAITA("16", a2);
        MF16(a2, 32);
        WAITA("0", a3);
        MF16(a3, 48);

        // ---- epilogue: add preloaded proj, sigmoid, stash in own sg cols ----
        // C/D layout (m74/m101): col = lane&31, row = (r&3) + 8*(r>>2) + 4*(lane>>5)
        #pragma unroll
        for (int r = 0; r < 16; r++) {
            int row = (r & 3) + 8 * (r >> 2) + 4 * half;
            sg[row][wv * 32 + l31] = sigm(acc0[r] + acc1[r] + pr[r]);
        }
        // in-wave cross-lane handoff: wait LDS writes, no inter-wave barrier
        asm volatile("s_waitcnt lgkmcnt(0)" ::: "memory");

        // ---- pointwise: thread owns (row = tid&31, hcols uq*4..+4) ----
        {
            const float rr = (clsW[wv][cur][urow] > 0) ? 1.0f : 0.0f;
            unsigned short hv[4];
            #pragma unroll
            for (int q = 0; q < 4; q++) {
                float4 gq = *reinterpret_cast<const float4*>(&sg[urow][uq * 16 + q * 4]);
                float cn = (gq.z * gq.y + Cst[q] * gq.x) * rr;   // (g*i + C*f)*r
                Cst[q] = cn;
                float hvv = gq.w * tanh_(cn);
                hv[q] = f2b(hvv);
                if (s == SS - 1)
                    hf32[(size_t)(m0 + urow) * HH + ng * 16 + uq * 4 + q] = hvv;
            }
            unsigned long long pk = (unsigned long long)hv[0]
                                  | ((unsigned long long)hv[1] << 16)
                                  | ((unsigned long long)hv[2] << 32)
                                  | ((unsigned long long)hv[3] << 48);
            asm volatile("global_store_dwordx2 %0, %1, off sc0 sc1" :: "v"(sb), "v"(pk) : "memory");
            if (s + 1 < SS && lane < 32)
                clsW[wv][cur ^ 1][lane] = x[(size_t)(m0 + lane) * SS + s + 1];
        }

        // ---- per-wave barrier leg: drain own h-stores, post arrival, poll ----
        if (s < SS - 1) {
            asm volatile("s_waitcnt vmcnt(0)" ::: "memory");   // own stores at L3
            if (lane == 0) {
                int one = 1;
                asm volatile("global_atomic_add %0, %1, off"
                             :: "v"(ctrAddr), "v"(one) : "memory");
            }
            PRLOAD(pr, clsW[wv][cur ^ 1]); // next step's proj gather, rides the poll
            const int tv = (s + 1) << 4;   // 16 waves per arrival line
            int got;
            do {   // one wide poll: lane l watches line l&7 (single RT/iter)
                asm volatile("global_load_dword %0, %1, off sc0 sc1\n\t"
                             "s_waitcnt vmcnt(0)"
                             : "=v"(got) : "v"(pollAddr) : "memory");
            } while (__ballot(got >= tv) != ~0ull);
        }
    }
}

// ---------------- final projection + log_softmax (k-split 4-way) ----------------
__global__ void k_final(const float* __restrict__ hf32, const float* __restrict__ Wph,
                        const float* __restrict__ bp, float* __restrict__ out) {
    __shared__ float part[512];
    __shared__ float red[128];
    const int b = blockIdx.x, tid = threadIdx.x;
    const int c = tid & 127, q = tid >> 7;     // q: k-quarter 0..3
    const float* hr = hf32 + (size_t)b * HH + q * 256;
    const float* wp = Wph + (size_t)(q * 256) * NCC + c;
    float acc = 0.0f;
    #pragma unroll 8
    for (int k = 0; k < 256; k++) acc += hr[k] * wp[(size_t)k * NCC];
    part[tid] = acc;
    __syncthreads();
    float a = 0.0f;
    if (tid < 128) {
        a = part[c] + part[c + 128] + part[c + 256] + part[c + 384] + bp[c];
        red[c] = a;
    }
    __syncthreads();
    for (int st = 64; st > 0; st >>= 1) {
        if (tid < st) red[tid] = fmaxf(red[tid], red[tid + st]);
        __syncthreads();
    }
    float m = red[0];
    __syncthreads();
    if (tid < 128) red[tid] = __expf(a - m);
    __syncthreads();
    for (int st = 64; st > 0; st >>= 1) {
        if (tid < st) red[tid] += red[tid + st];
        __syncthreads();
    }
    if (tid < 128) out[(size_t)b * NCC + tid] = a - m - __logf(red[0]);
}

extern "C" void kernel_launch(void* const* d_in, const int* in_sizes, int n_in,
                              void* d_out, int out_size, void* d_ws, size_t ws_size,
                              hipStream_t stream) {
    const int*   x   = (const int*)  d_in[0];
    const float* emb = (const float*)d_in[1];
    const float* Wfx = (const float*)d_in[2];
    const float* Wfh = (const float*)d_in[3];
    const float* bf_ = (const float*)d_in[4];
    const float* Wix = (const float*)d_in[5];
    const float* Wih = (const float*)d_in[6];
    const float* bi_ = (const float*)d_in[7];
    const float* Wgx = (const float*)d_in[8];
    const float* Wgh = (const float*)d_in[9];
    const float* bg_ = (const float*)d_in[10];
    const float* Wox = (const float*)d_in[11];
    const float* Woh = (const float*)d_in[12];
    const float* bo_ = (const float*)d_in[13];
    const float* Wph = (const float*)d_in[14];
    const float* bp_ = (const float*)d_in[15];
    float* out = (float*)d_out;

    char* ws = (char*)d_ws;
    unsigned short* WhT   = (unsigned short*)(ws);              // 8 MB
    float*          proj  = (float*)(ws + 8388608);             // 2.02 MB -> ends 10502144
    int*            flags = (int*)(ws + 10502656);              // 64 KB (16384 ints)
    unsigned short* hb0   = (unsigned short*)(ws + 10568192);   // 256 KB
    unsigned short* hb1   = (unsigned short*)(ws + 10830336);   // 256 KB
    float*          hf32  = (float*)(ws + 11092480);            // 512 KB -> ends ~11.6 MB

    k_pre<<<dim3(4864), dim3(256), 0, stream>>>(hb0, flags, Wfh, Wih, Wgh, Woh, WhT,
                                                emb, Wfx, Wix, Wgx, Wox,
                                                bf_, bi_, bg_, bo_, proj);
    k_scan<<<dim3(NWG), dim3(128), 0, stream>>>(x, proj, WhT, hb0, hb1, hf32, flags);
    k_final<<<dim3(128), dim3(512), 0, stream>>>(hf32, Wph, bp_, out);
}